// Round 1
// baseline (2473.457 us; speedup 1.0000x reference)
//
#include <hip/hip_runtime.h>

#define N_TOK 16384
#define C_DIM 1024
#define E_NUM 8
#define H_DIM 4096
#define CAPACITY 4096
#define LB_W 0.01f

typedef __bf16 bf16;
typedef bf16 bf16x8 __attribute__((ext_vector_type(8)));
typedef bf16 bf16x4 __attribute__((ext_vector_type(4)));
typedef float f32x4 __attribute__((ext_vector_type(4)));

__device__ __forceinline__ void gld_lds16(const void* g, void* l) {
  __builtin_amdgcn_global_load_lds((const __attribute__((address_space(1))) void*)g,
                                   (__attribute__((address_space(3))) void*)l,
                                   16, 0, 0);
}

// ---------------- routing: logits, noisy top-2, gates ----------------
__global__ void route_kernel(const float* __restrict__ x,
                             const float* __restrict__ noise,
                             const float* __restrict__ w_route,
                             const float* __restrict__ b_route,
                             const float* __restrict__ w_noise,
                             const float* __restrict__ b_noise,
                             float* __restrict__ gates,
                             int* __restrict__ maskT) {
  const int lane = threadIdx.x;                         // 0..63
  const int n = blockIdx.x * blockDim.y + threadIdx.y;  // token
  float xv[16];
#pragma unroll
  for (int i = 0; i < 16; ++i) xv[i] = x[(size_t)n * C_DIM + lane + 64 * i];
  float lr[E_NUM], ln[E_NUM];
#pragma unroll
  for (int e = 0; e < E_NUM; ++e) {
    float sr = 0.f, sn = 0.f;
#pragma unroll
    for (int i = 0; i < 16; ++i) {
      sr += xv[i] * w_route[e * C_DIM + lane + 64 * i];
      sn += xv[i] * w_noise[e * C_DIM + lane + 64 * i];
    }
#pragma unroll
    for (int off = 32; off; off >>= 1) {
      sr += __shfl_xor(sr, off, 64);
      sn += __shfl_xor(sn, off, 64);
    }
    lr[e] = sr;
    ln[e] = sn;
  }
  if (lane == 0) {
    float noisy[E_NUM];
#pragma unroll
    for (int e = 0; e < E_NUM; ++e) {
      float z = ln[e] + b_noise[e];
      float sp = fmaxf(z, 0.f) + log1pf(expf(-fabsf(z)));  // stable softplus
      noisy[e] = lr[e] + b_route[e] + noise[n * E_NUM + e] * sp;
    }
    int i1 = 0;
    float v1 = noisy[0];
#pragma unroll
    for (int e = 1; e < E_NUM; ++e)
      if (noisy[e] > v1) { v1 = noisy[e]; i1 = e; }
    int i2 = -1;
    float v2 = -3.0e38f;
#pragma unroll
    for (int e = 0; e < E_NUM; ++e)
      if (e != i1 && noisy[e] > v2) { v2 = noisy[e]; i2 = e; }
    float e2 = expf(v2 - v1);
    float denom = 1.f + e2;
#pragma unroll
    for (int e = 0; e < E_NUM; ++e) {
      float g = (e == i1) ? (1.f / denom) : ((e == i2) ? (e2 / denom) : 0.f);
      gates[n * E_NUM + e] = g;
      maskT[(size_t)e * N_TOK + n] = (e == i1 || e == i2) ? 1 : 0;
    }
  }
}

// ---------------- per-expert capacity scan (deterministic token order) -------
__global__ void scan_kernel(const int* __restrict__ maskT,
                            const float* __restrict__ gates,
                            int* __restrict__ tok, float* __restrict__ gslot) {
  const int e = blockIdx.x;
  const int l = threadIdx.x;  // 64
  int running = 0;
  for (int chunk = 0; chunk < N_TOK / 64; ++chunk) {
    int n = chunk * 64 + l;
    int m = maskT[(size_t)e * N_TOK + n];
    int v = m;
#pragma unroll
    for (int off = 1; off < 64; off <<= 1) {
      int u = __shfl_up(v, off, 64);
      if (l >= off) v += u;
    }
    int pos = running + v - m;  // exclusive prefix
    if (m && pos < CAPACITY) {
      tok[e * CAPACITY + pos] = n;
      gslot[e * CAPACITY + pos] = gates[n * E_NUM + e];
    }
    running += __shfl(v, 63, 64);
  }
}

// ---------------- load-balance loss reduction ----------------
__global__ void frac_kernel(const float* __restrict__ gates,
                            float* __restrict__ fracsum) {
  __shared__ float sm[E_NUM];
  int t = threadIdx.x;
  if (t < E_NUM) sm[t] = 0.f;
  __syncthreads();
  int g0 = blockIdx.x * 256 + t;
  float p = 0.f;
#pragma unroll
  for (int i = 0; i < (N_TOK * E_NUM) / (256 * 64); ++i)
    p += gates[g0 + i * 256 * 64];
  atomicAdd(&sm[t & 7], p);
  __syncthreads();
  if (t < E_NUM) atomicAdd(&fracsum[t], sm[t]);
}

__global__ void lb_kernel(const float* __restrict__ fracsum,
                          float* __restrict__ out_scalar) {
  if (threadIdx.x == 0) {
    float s = 0.f;
#pragma unroll
    for (int e = 0; e < E_NUM; ++e) {
      float f = fracsum[e] / (float)N_TOK - 0.125f;
      s += f * f;
    }
    out_scalar[0] = LB_W * (s / (float)E_NUM);
  }
}

// ---------------- fp32 (E,R,S) -> bf16 (E,S,R) transpose+convert -------------
__global__ void transpose_cvt(const float* __restrict__ src,
                              bf16* __restrict__ dst, int R, int S) {
  __shared__ float tile[32][33];
  const int e = blockIdx.z;
  const int r0 = blockIdx.y * 32;
  const int s0 = blockIdx.x * 32;
  const int t = threadIdx.x;  // 256
  const int rr = t >> 3, cc = (t & 7) * 4;
  const float4 v = *(const float4*)(src + ((size_t)e * R + (r0 + rr)) * S + s0 + cc);
  tile[rr][cc + 0] = v.x;
  tile[rr][cc + 1] = v.y;
  tile[rr][cc + 2] = v.z;
  tile[rr][cc + 3] = v.w;
  __syncthreads();
  bf16x4 o;
#pragma unroll
  for (int i = 0; i < 4; ++i) o[i] = (bf16)tile[cc + i][rr];
  *(bf16x4*)(dst + ((size_t)e * S + (s0 + rr)) * R + r0 + cc) = o;
}

// ---------------- gather selected token rows into xe (bf16) -----------------
__global__ void gather_xe(const float* __restrict__ x,
                          const int* __restrict__ tok, bf16* __restrict__ xe) {
  const int row = blockIdx.x;  // e*CAP + slot
  const int t = tok[row];
  const int c = threadIdx.x * 8;  // 128 threads * 8 = 1024
  bf16x8 v;
  if (t >= 0) {
    const float4* xp = (const float4*)(x + (size_t)t * C_DIM + c);
    float4 a = xp[0], b = xp[1];
    v[0] = (bf16)a.x; v[1] = (bf16)a.y; v[2] = (bf16)a.z; v[3] = (bf16)a.w;
    v[4] = (bf16)b.x; v[5] = (bf16)b.y; v[6] = (bf16)b.z; v[7] = (bf16)b.w;
  } else {
#pragma unroll
    for (int i = 0; i < 8; ++i) v[i] = (bf16)0.f;
  }
  *(bf16x8*)(xe + (size_t)row * C_DIM + c) = v;
}

// ---------------- m97-style bf16 GEMM: C = A(MxK,kfast) * B(NxK,kfast)^T ----
// EPI=0: Hout = bf16(relu(acc + bias[col]))
// EPI=1: if tok[row]>=0: atomicAdd(Out[tok[row]*C + col], gslot[row]*(acc+bias[col]))
template <int EPI>
__global__ __launch_bounds__(256) void gemm_bt(
    const bf16* __restrict__ A, const bf16* __restrict__ B, int Kk, int Nn,
    const float* __restrict__ bias, bf16* __restrict__ Hout,
    const int* __restrict__ tok, const float* __restrict__ gslot,
    float* __restrict__ Out) {
  __shared__ bf16 As[128 * 32];
  __shared__ bf16 Bs[128 * 32];
  const int t = threadIdx.x;
  const int lane = t & 63;
  const int w = t >> 6;
  const int wm = (w >> 1) * 64;
  const int wn = (w & 1) * 64;
  const int bm = blockIdx.y * 128;
  const int bn = blockIdx.x * 128;

  f32x4 acc[4][4] = {};

  const int rowA = t >> 2;          // 0..63
  const int partA = (t & 3) << 4;   // byte offset within 64B row
  const char* aP1 = (const char*)(A + (size_t)(bm + rowA) * Kk) + partA;
  const char* aP2 = (const char*)(A + (size_t)(bm + 64 + rowA) * Kk) + partA;
  const char* bP1 = (const char*)(B + (size_t)(bn + rowA) * Kk) + partA;
  const char* bP2 = (const char*)(B + (size_t)(bn + 64 + rowA) * Kk) + partA;
  char* asD1 = (char*)As + (t & 192) * 16;
  char* asD2 = (char*)As + 4096 + (t & 192) * 16;
  char* bsD1 = (char*)Bs + (t & 192) * 16;
  char* bsD2 = (char*)Bs + 4096 + (t & 192) * 16;

  for (int kt = 0; kt < Kk; kt += 32) {
    gld_lds16(aP1 + kt * 2, asD1);
    gld_lds16(aP2 + kt * 2, asD2);
    gld_lds16(bP1 + kt * 2, bsD1);
    gld_lds16(bP2 + kt * 2, bsD2);
    __syncthreads();
    bf16x8 af[4], bfr[4];
#pragma unroll
    for (int i = 0; i < 4; ++i) {
      af[i] = *(const bf16x8*)(As + (wm + i * 16 + (lane & 15)) * 32 + (lane >> 4) * 8);
      bfr[i] = *(const bf16x8*)(Bs + (wn + i * 16 + (lane & 15)) * 32 + (lane >> 4) * 8);
    }
#pragma unroll
    for (int i = 0; i < 4; ++i)
#pragma unroll
      for (int j = 0; j < 4; ++j)
        acc[i][j] = __builtin_amdgcn_mfma_f32_16x16x32_bf16(af[i], bfr[j], acc[i][j], 0, 0, 0);
    __syncthreads();
  }

  if (EPI == 0) {
#pragma unroll
    for (int i = 0; i < 4; ++i) {
      const int rbase = bm + wm + i * 16 + (lane >> 4) * 4;
#pragma unroll
      for (int j = 0; j < 4; ++j) {
        const int col = bn + wn + j * 16 + (lane & 15);
        const float b = bias[col];
#pragma unroll
        for (int r = 0; r < 4; ++r) {
          float v = acc[i][j][r] + b;
          Hout[(size_t)(rbase + r) * Nn + col] = (bf16)fmaxf(v, 0.f);
        }
      }
    }
  } else {
#pragma unroll
    for (int i = 0; i < 4; ++i) {
      const int rbase = bm + wm + i * 16 + (lane >> 4) * 4;
#pragma unroll
      for (int r = 0; r < 4; ++r) {
        const int row = rbase + r;
        const int tk = tok[row];
        if (tk >= 0) {
          const float g = gslot[row];
#pragma unroll
          for (int j = 0; j < 4; ++j) {
            const int col = bn + wn + j * 16 + (lane & 15);
            atomicAdd(Out + (size_t)tk * C_DIM + col, g * (acc[i][j][r] + bias[col]));
          }
        }
      }
    }
  }
}

extern "C" void kernel_launch(void* const* d_in, const int* in_sizes, int n_in,
                              void* d_out, int out_size, void* d_ws,
                              size_t ws_size, hipStream_t stream) {
  const float* x = (const float*)d_in[0];
  const float* noise = (const float*)d_in[1];
  const float* w_route = (const float*)d_in[2];
  const float* b_route = (const float*)d_in[3];
  const float* w_noise = (const float*)d_in[4];
  const float* b_noise = (const float*)d_in[5];
  const float* w1 = (const float*)d_in[6];
  const float* b1 = (const float*)d_in[7];
  const float* w2 = (const float*)d_in[8];
  const float* b2 = (const float*)d_in[9];
  float* out = (float*)d_out;

  char* ws = (char*)d_ws;
  size_t off = 0;
  auto alloc = [&](size_t bytes) {
    char* p = ws + off;
    off += (bytes + 255) & ~(size_t)255;
    return p;
  };
  float* gates = (float*)alloc((size_t)N_TOK * E_NUM * 4);
  int* maskT = (int*)alloc((size_t)N_TOK * E_NUM * 4);
  int* tok = (int*)alloc((size_t)E_NUM * CAPACITY * 4);
  float* gslot = (float*)alloc((size_t)E_NUM * CAPACITY * 4);
  float* fracsum = (float*)alloc(256);
  bf16* xe = (bf16*)alloc((size_t)E_NUM * CAPACITY * C_DIM * 2);
  bf16* w1t = (bf16*)alloc((size_t)E_NUM * H_DIM * C_DIM * 2);
  bf16* w2t = (bf16*)alloc((size_t)E_NUM * C_DIM * H_DIM * 2);
  bf16* hbuf = (bf16*)alloc((size_t)CAPACITY * H_DIM * 2);
  if (off > ws_size) return;  // insufficient scratch -> visible failure

  hipMemsetAsync(d_out, 0, (size_t)out_size * 4, stream);
  hipMemsetAsync(tok, 0xFF, (size_t)E_NUM * CAPACITY * 4, stream);
  hipMemsetAsync(fracsum, 0, 256, stream);

  // weight transposes (no deps on routing)
  transpose_cvt<<<dim3(H_DIM / 32, C_DIM / 32, E_NUM), 256, 0, stream>>>(w1, w1t, C_DIM, H_DIM);
  transpose_cvt<<<dim3(C_DIM / 32, H_DIM / 32, E_NUM), 256, 0, stream>>>(w2, w2t, H_DIM, C_DIM);

  route_kernel<<<dim3(N_TOK / 4), dim3(64, 4), 0, stream>>>(
      x, noise, w_route, b_route, w_noise, b_noise, gates, maskT);
  scan_kernel<<<E_NUM, 64, 0, stream>>>(maskT, gates, tok, gslot);
  frac_kernel<<<64, 256, 0, stream>>>(gates, fracsum);
  lb_kernel<<<1, 64, 0, stream>>>(fracsum, out + (size_t)N_TOK * C_DIM);

  gather_xe<<<E_NUM * CAPACITY, 128, 0, stream>>>(x, tok, xe);

  for (int e = 0; e < E_NUM; ++e) {
    gemm_bt<0><<<dim3(H_DIM / 128, CAPACITY / 128), 256, 0, stream>>>(
        xe + (size_t)e * CAPACITY * C_DIM, w1t + (size_t)e * H_DIM * C_DIM,
        C_DIM, H_DIM, b1 + (size_t)e * H_DIM, hbuf, nullptr, nullptr, nullptr);
    gemm_bt<1><<<dim3(C_DIM / 128, CAPACITY / 128), 256, 0, stream>>>(
        hbuf, w2t + (size_t)e * C_DIM * H_DIM, H_DIM, C_DIM,
        b2 + (size_t)e * C_DIM, nullptr, tok + e * CAPACITY,
        gslot + e * CAPACITY, out);
  }
}

// Round 2
// 1498.971 us; speedup vs baseline: 1.6501x; 1.6501x over previous
//
#include <hip/hip_runtime.h>

#define N_TOK 16384
#define C_DIM 1024
#define E_NUM 8
#define H_DIM 4096
#define CAPACITY 4096
#define LB_W 0.01f

typedef __bf16 bf16;
typedef bf16 bf16x8 __attribute__((ext_vector_type(8)));
typedef bf16 bf16x4 __attribute__((ext_vector_type(4)));
typedef float f32x4 __attribute__((ext_vector_type(4)));

__device__ __forceinline__ void gld_lds16(const void* g, void* l) {
  __builtin_amdgcn_global_load_lds((const __attribute__((address_space(1))) void*)g,
                                   (__attribute__((address_space(3))) void*)l,
                                   16, 0, 0);
}

// ---------------- routing: logits, noisy top-2, gates ----------------
__global__ void route_kernel(const float* __restrict__ x,
                             const float* __restrict__ noise,
                             const float* __restrict__ w_route,
                             const float* __restrict__ b_route,
                             const float* __restrict__ w_noise,
                             const float* __restrict__ b_noise,
                             float* __restrict__ gates,
                             int* __restrict__ maskT) {
  const int lane = threadIdx.x;                         // 0..63
  const int n = blockIdx.x * blockDim.y + threadIdx.y;  // token
  float xv[16];
#pragma unroll
  for (int i = 0; i < 16; ++i) xv[i] = x[(size_t)n * C_DIM + lane + 64 * i];
  float lr[E_NUM], ln[E_NUM];
#pragma unroll
  for (int e = 0; e < E_NUM; ++e) {
    float sr = 0.f, sn = 0.f;
#pragma unroll
    for (int i = 0; i < 16; ++i) {
      sr += xv[i] * w_route[e * C_DIM + lane + 64 * i];
      sn += xv[i] * w_noise[e * C_DIM + lane + 64 * i];
    }
#pragma unroll
    for (int off = 32; off; off >>= 1) {
      sr += __shfl_xor(sr, off, 64);
      sn += __shfl_xor(sn, off, 64);
    }
    lr[e] = sr;
    ln[e] = sn;
  }
  if (lane == 0) {
    float noisy[E_NUM];
#pragma unroll
    for (int e = 0; e < E_NUM; ++e) {
      float z = ln[e] + b_noise[e];
      float sp = fmaxf(z, 0.f) + log1pf(expf(-fabsf(z)));  // stable softplus
      noisy[e] = lr[e] + b_route[e] + noise[n * E_NUM + e] * sp;
    }
    int i1 = 0;
    float v1 = noisy[0];
#pragma unroll
    for (int e = 1; e < E_NUM; ++e)
      if (noisy[e] > v1) { v1 = noisy[e]; i1 = e; }
    int i2 = -1;
    float v2 = -3.0e38f;
#pragma unroll
    for (int e = 0; e < E_NUM; ++e)
      if (e != i1 && noisy[e] > v2) { v2 = noisy[e]; i2 = e; }
    float e2 = expf(v2 - v1);
    float denom = 1.f + e2;
#pragma unroll
    for (int e = 0; e < E_NUM; ++e) {
      float g = (e == i1) ? (1.f / denom) : ((e == i2) ? (e2 / denom) : 0.f);
      gates[n * E_NUM + e] = g;
      maskT[(size_t)e * N_TOK + n] = (e == i1 || e == i2) ? 1 : 0;
    }
  }
}

// -------- per-expert capacity scan, parallel (1024 thr/expert, 16 tok/thr) --
__global__ __launch_bounds__(1024) void scan_kernel(
    const int* __restrict__ maskT, const float* __restrict__ gates,
    int* __restrict__ tok, float* __restrict__ gslot) {
  const int e = blockIdx.x;
  const int t = threadIdx.x;   // 0..1023
  const int lane = t & 63, w = t >> 6;
  __shared__ int wt[16];

  int4 mv[4];
#pragma unroll
  for (int i = 0; i < 4; ++i)
    mv[i] = *(const int4*)(maskT + (size_t)e * N_TOK + t * 16 + i * 4);
  const int* m = (const int*)mv;
  int s = 0;
#pragma unroll
  for (int i = 0; i < 16; ++i) s += m[i];

  int v = s;  // inclusive wave scan over thread sums
#pragma unroll
  for (int off = 1; off < 64; off <<= 1) {
    int u = __shfl_up(v, off, 64);
    if (lane >= off) v += u;
  }
  if (lane == 63) wt[w] = v;
  __syncthreads();
  int woff = 0;
#pragma unroll
  for (int i = 0; i < 16; ++i)
    if (i < w) woff += wt[i];

  int pos = woff + v - s;  // exclusive prefix for this thread's 16 tokens
#pragma unroll
  for (int i = 0; i < 16; ++i) {
    if (m[i] && pos < CAPACITY) {
      int n = t * 16 + i;
      tok[e * CAPACITY + pos] = n;
      gslot[e * CAPACITY + pos] = gates[n * E_NUM + e];
    }
    pos += m[i];
  }
}

// ---------------- load-balance loss reduction ----------------
__global__ void frac_kernel(const float* __restrict__ gates,
                            float* __restrict__ fracsum) {
  __shared__ float sm[E_NUM];
  int t = threadIdx.x;
  if (t < E_NUM) sm[t] = 0.f;
  __syncthreads();
  int g0 = blockIdx.x * 256 + t;
  float p = 0.f;
#pragma unroll
  for (int i = 0; i < (N_TOK * E_NUM) / (256 * 64); ++i)
    p += gates[g0 + i * 256 * 64];
  atomicAdd(&sm[t & 7], p);
  __syncthreads();
  if (t < E_NUM) atomicAdd(&fracsum[t], sm[t]);
}

__global__ void lb_kernel(const float* __restrict__ fracsum,
                          float* __restrict__ out_scalar) {
  if (threadIdx.x == 0) {
    float s = 0.f;
#pragma unroll
    for (int e = 0; e < E_NUM; ++e) {
      float f = fracsum[e] / (float)N_TOK - 0.125f;
      s += f * f;
    }
    out_scalar[0] = LB_W * (s / (float)E_NUM);
  }
}

// ---------------- fp32 (E,R,S) -> bf16 (E,S,R) transpose+convert -------------
__global__ void transpose_cvt(const float* __restrict__ src,
                              bf16* __restrict__ dst, int R, int S) {
  __shared__ float tile[32][33];
  const int e = blockIdx.z;
  const int r0 = blockIdx.y * 32;
  const int s0 = blockIdx.x * 32;
  const int t = threadIdx.x;  // 256
  const int rr = t >> 3, cc = (t & 7) * 4;
  const float4 v = *(const float4*)(src + ((size_t)e * R + (r0 + rr)) * S + s0 + cc);
  tile[rr][cc + 0] = v.x;
  tile[rr][cc + 1] = v.y;
  tile[rr][cc + 2] = v.z;
  tile[rr][cc + 3] = v.w;
  __syncthreads();
  bf16x4 o;
#pragma unroll
  for (int i = 0; i < 4; ++i) o[i] = (bf16)tile[cc + i][rr];
  *(bf16x4*)(dst + ((size_t)e * S + (s0 + rr)) * R + r0 + cc) = o;
}

// ---------------- gather selected token rows into xe (bf16) -----------------
__global__ void gather_xe(const float* __restrict__ x,
                          const int* __restrict__ tok, bf16* __restrict__ xe) {
  const int row = blockIdx.x;  // e*CAP + slot
  const int t = tok[row];
  const int c = threadIdx.x * 8;  // 128 threads * 8 = 1024
  bf16x8 v;
  if (t >= 0) {
    const float4* xp = (const float4*)(x + (size_t)t * C_DIM + c);
    float4 a = xp[0], b = xp[1];
    v[0] = (bf16)a.x; v[1] = (bf16)a.y; v[2] = (bf16)a.z; v[3] = (bf16)a.w;
    v[4] = (bf16)b.x; v[5] = (bf16)b.y; v[6] = (bf16)b.z; v[7] = (bf16)b.w;
  } else {
#pragma unroll
    for (int i = 0; i < 8; ++i) v[i] = (bf16)0.f;
  }
  *(bf16x8*)(xe + (size_t)row * C_DIM + c) = v;
}

// ------ m97-style bf16 GEMM, expert-batched over blockIdx.z ------
// C = A(MxK,kfast) * B(NxK,kfast)^T per z-slice
// EPI=0: Hout = bf16(relu(acc + bias[col]))
// EPI=1: if tok[row]>=0: atomicAdd(Out[tok[row]*C + col], gslot[row]*(acc+bias[col]))
template <int EPI>
__global__ __launch_bounds__(256) void gemm_bt(
    const bf16* __restrict__ A0, size_t aStride, const bf16* __restrict__ B0,
    size_t bStride, int Kk, int Nn, const float* __restrict__ bias0,
    int biasStride, bf16* __restrict__ Hout0, size_t hStride,
    const int* __restrict__ tok0, const float* __restrict__ gslot0,
    float* __restrict__ Out) {
  const int z = blockIdx.z;
  const bf16* A = A0 + (size_t)z * aStride;
  const bf16* B = B0 + (size_t)z * bStride;
  const float* bias = bias0 + (size_t)z * biasStride;

  __shared__ bf16 As[128 * 32];
  __shared__ bf16 Bs[128 * 32];
  const int t = threadIdx.x;
  const int lane = t & 63;
  const int w = t >> 6;
  const int wm = (w >> 1) * 64;
  const int wn = (w & 1) * 64;
  const int bm = blockIdx.y * 128;
  const int bn = blockIdx.x * 128;

  f32x4 acc[4][4] = {};

  const int rowA = t >> 2;         // 0..63
  const int partA = (t & 3) << 4;  // byte offset within 64B row
  const char* aP1 = (const char*)(A + (size_t)(bm + rowA) * Kk) + partA;
  const char* aP2 = (const char*)(A + (size_t)(bm + 64 + rowA) * Kk) + partA;
  const char* bP1 = (const char*)(B + (size_t)(bn + rowA) * Kk) + partA;
  const char* bP2 = (const char*)(B + (size_t)(bn + 64 + rowA) * Kk) + partA;
  char* asD1 = (char*)As + (t & 192) * 16;
  char* asD2 = (char*)As + 4096 + (t & 192) * 16;
  char* bsD1 = (char*)Bs + (t & 192) * 16;
  char* bsD2 = (char*)Bs + 4096 + (t & 192) * 16;

  for (int kt = 0; kt < Kk; kt += 32) {
    gld_lds16(aP1 + kt * 2, asD1);
    gld_lds16(aP2 + kt * 2, asD2);
    gld_lds16(bP1 + kt * 2, bsD1);
    gld_lds16(bP2 + kt * 2, bsD2);
    __syncthreads();
    bf16x8 af[4], bfr[4];
#pragma unroll
    for (int i = 0; i < 4; ++i) {
      af[i] = *(const bf16x8*)(As + (wm + i * 16 + (lane & 15)) * 32 + (lane >> 4) * 8);
      bfr[i] = *(const bf16x8*)(Bs + (wn + i * 16 + (lane & 15)) * 32 + (lane >> 4) * 8);
    }
#pragma unroll
    for (int i = 0; i < 4; ++i)
#pragma unroll
      for (int j = 0; j < 4; ++j)
        acc[i][j] = __builtin_amdgcn_mfma_f32_16x16x32_bf16(af[i], bfr[j], acc[i][j], 0, 0, 0);
    __syncthreads();
  }

  if (EPI == 0) {
    bf16* Hout = Hout0 + (size_t)z * hStride;
#pragma unroll
    for (int i = 0; i < 4; ++i) {
      const int rbase = bm + wm + i * 16 + (lane >> 4) * 4;
#pragma unroll
      for (int j = 0; j < 4; ++j) {
        const int col = bn + wn + j * 16 + (lane & 15);
        const float b = bias[col];
#pragma unroll
        for (int r = 0; r < 4; ++r) {
          float v = acc[i][j][r] + b;
          Hout[(size_t)(rbase + r) * Nn + col] = (bf16)fmaxf(v, 0.f);
        }
      }
    }
  } else {
    const int* tok = tok0 + (size_t)z * CAPACITY;
    const float* gslot = gslot0 + (size_t)z * CAPACITY;
#pragma unroll
    for (int i = 0; i < 4; ++i) {
      const int rbase = bm + wm + i * 16 + (lane >> 4) * 4;
#pragma unroll
      for (int r = 0; r < 4; ++r) {
        const int row = rbase + r;
        const int tk = tok[row];
        if (tk >= 0) {
          const float g = gslot[row];
#pragma unroll
          for (int j = 0; j < 4; ++j) {
            const int col = bn + wn + j * 16 + (lane & 15);
            atomicAdd(Out + (size_t)tk * C_DIM + col, g * (acc[i][j][r] + bias[col]));
          }
        }
      }
    }
  }
}

extern "C" void kernel_launch(void* const* d_in, const int* in_sizes, int n_in,
                              void* d_out, int out_size, void* d_ws,
                              size_t ws_size, hipStream_t stream) {
  const float* x = (const float*)d_in[0];
  const float* noise = (const float*)d_in[1];
  const float* w_route = (const float*)d_in[2];
  const float* b_route = (const float*)d_in[3];
  const float* w_noise = (const float*)d_in[4];
  const float* b_noise = (const float*)d_in[5];
  const float* w1 = (const float*)d_in[6];
  const float* b1 = (const float*)d_in[7];
  const float* w2 = (const float*)d_in[8];
  const float* b2 = (const float*)d_in[9];
  float* out = (float*)d_out;

  char* ws = (char*)d_ws;
  size_t off = 0;
  auto alloc = [&](size_t bytes) {
    char* p = ws + off;
    off += (bytes + 255) & ~(size_t)255;
    return p;
  };
  float* gates = (float*)alloc((size_t)N_TOK * E_NUM * 4);
  int* maskT = (int*)alloc((size_t)N_TOK * E_NUM * 4);
  int* tok = (int*)alloc((size_t)E_NUM * CAPACITY * 4);
  float* gslot = (float*)alloc((size_t)E_NUM * CAPACITY * 4);
  float* fracsum = (float*)alloc(256);
  bf16* xe = (bf16*)alloc((size_t)E_NUM * CAPACITY * C_DIM * 2);
  bf16* w1t = (bf16*)alloc((size_t)E_NUM * H_DIM * C_DIM * 2);
  bf16* w2t = (bf16*)alloc((size_t)E_NUM * C_DIM * H_DIM * 2);

  // Adaptive expert-group size for the h buffer (32 MB/expert); graph-safe
  // because ws_size is constant across calls.
  const size_t hPer = (size_t)CAPACITY * H_DIM * 2;
  size_t hAvail = (ws_size > off) ? (ws_size - off) : 0;
  int G = (int)(hAvail / hPer);
  if (G > E_NUM) G = E_NUM;
  if (G < 1) return;                 // insufficient scratch -> visible failure
  while (E_NUM % G) --G;             // uniform batches: G in {8,4,2,1}
  bf16* hbuf = (bf16*)alloc((size_t)G * hPer);

  hipMemsetAsync(d_out, 0, (size_t)out_size * 4, stream);
  hipMemsetAsync(tok, 0xFF, (size_t)E_NUM * CAPACITY * 4, stream);
  hipMemsetAsync(fracsum, 0, 256, stream);

  // weight transposes (no deps on routing)
  transpose_cvt<<<dim3(H_DIM / 32, C_DIM / 32, E_NUM), 256, 0, stream>>>(w1, w1t, C_DIM, H_DIM);
  transpose_cvt<<<dim3(C_DIM / 32, H_DIM / 32, E_NUM), 256, 0, stream>>>(w2, w2t, H_DIM, C_DIM);

  route_kernel<<<dim3(N_TOK / 4), dim3(64, 4), 0, stream>>>(
      x, noise, w_route, b_route, w_noise, b_noise, gates, maskT);
  scan_kernel<<<E_NUM, 1024, 0, stream>>>(maskT, gates, tok, gslot);
  frac_kernel<<<64, 256, 0, stream>>>(gates, fracsum);
  lb_kernel<<<1, 64, 0, stream>>>(fracsum, out + (size_t)N_TOK * C_DIM);

  gather_xe<<<E_NUM * CAPACITY, 128, 0, stream>>>(x, tok, xe);

  for (int e0 = 0; e0 < E_NUM; e0 += G) {
    gemm_bt<0><<<dim3(H_DIM / 128, CAPACITY / 128, G), 256, 0, stream>>>(
        xe + (size_t)e0 * CAPACITY * C_DIM, (size_t)CAPACITY * C_DIM,
        w1t + (size_t)e0 * H_DIM * C_DIM, (size_t)H_DIM * C_DIM,
        C_DIM, H_DIM, b1 + (size_t)e0 * H_DIM, H_DIM,
        hbuf, (size_t)CAPACITY * H_DIM, nullptr, nullptr, nullptr);
    gemm_bt<1><<<dim3(C_DIM / 128, CAPACITY / 128, G), 256, 0, stream>>>(
        hbuf, (size_t)CAPACITY * H_DIM,
        w2t + (size_t)e0 * C_DIM * H_DIM, (size_t)C_DIM * H_DIM,
        H_DIM, C_DIM, b2 + (size_t)e0 * C_DIM, C_DIM,
        nullptr, 0, tok + (size_t)e0 * CAPACITY, gslot + (size_t)e0 * CAPACITY, out);
  }
}

// Round 3
// 1468.250 us; speedup vs baseline: 1.6846x; 1.0209x over previous
//
#include <hip/hip_runtime.h>

#define N_TOK 16384
#define C_DIM 1024
#define E_NUM 8
#define H_DIM 4096
#define CAPACITY 4096
#define LB_W 0.01f

typedef __bf16 bf16;
typedef bf16 bf16x8 __attribute__((ext_vector_type(8)));
typedef bf16 bf16x4 __attribute__((ext_vector_type(4)));
typedef float f32x4 __attribute__((ext_vector_type(4)));

__device__ __forceinline__ void gld_lds16(const void* g, void* l) {
  __builtin_amdgcn_global_load_lds((const __attribute__((address_space(1))) void*)g,
                                   (__attribute__((address_space(3))) void*)l,
                                   16, 0, 0);
}

// ---- routing: logits, noisy top-2, gates. gatesT[e][n] = gate or -1 -------
__global__ void route_kernel(const float* __restrict__ x,
                             const float* __restrict__ noise,
                             const float* __restrict__ w_route,
                             const float* __restrict__ b_route,
                             const float* __restrict__ w_noise,
                             const float* __restrict__ b_noise,
                             float* __restrict__ gatesT) {
  const int lane = threadIdx.x;                         // 0..63
  const int n = blockIdx.x * blockDim.y + threadIdx.y;  // token
  float xv[16];
#pragma unroll
  for (int i = 0; i < 16; ++i) xv[i] = x[(size_t)n * C_DIM + lane + 64 * i];
  float lr[E_NUM], ln[E_NUM];
#pragma unroll
  for (int e = 0; e < E_NUM; ++e) {
    float sr = 0.f, sn = 0.f;
#pragma unroll
    for (int i = 0; i < 16; ++i) {
      sr += xv[i] * w_route[e * C_DIM + lane + 64 * i];
      sn += xv[i] * w_noise[e * C_DIM + lane + 64 * i];
    }
#pragma unroll
    for (int off = 32; off; off >>= 1) {
      sr += __shfl_xor(sr, off, 64);
      sn += __shfl_xor(sn, off, 64);
    }
    lr[e] = sr;
    ln[e] = sn;
  }
  if (lane == 0) {
    float noisy[E_NUM];
#pragma unroll
    for (int e = 0; e < E_NUM; ++e) {
      float z = ln[e] + b_noise[e];
      float sp = fmaxf(z, 0.f) + log1pf(expf(-fabsf(z)));  // stable softplus
      noisy[e] = lr[e] + b_route[e] + noise[n * E_NUM + e] * sp;
    }
    int i1 = 0;
    float v1 = noisy[0];
#pragma unroll
    for (int e = 1; e < E_NUM; ++e)
      if (noisy[e] > v1) { v1 = noisy[e]; i1 = e; }
    int i2 = -1;
    float v2 = -3.0e38f;
#pragma unroll
    for (int e = 0; e < E_NUM; ++e)
      if (e != i1 && noisy[e] > v2) { v2 = noisy[e]; i2 = e; }
    float e2 = expf(v2 - v1);
    float denom = 1.f + e2;
#pragma unroll
    for (int e = 0; e < E_NUM; ++e) {
      float g = (e == i1) ? (1.f / denom) : ((e == i2) ? (e2 / denom) : -1.f);
      gatesT[(size_t)e * N_TOK + n] = g;  // >=0 selected, -1 unselected
    }
  }
}

// -------- per-expert capacity scan, parallel (1024 thr/expert, 16 tok/thr) --
__global__ __launch_bounds__(1024) void scan_kernel(
    const float* __restrict__ gatesT, int* __restrict__ tok,
    float* __restrict__ gslot) {
  const int e = blockIdx.x;
  const int t = threadIdx.x;  // 0..1023
  const int lane = t & 63, w = t >> 6;
  __shared__ int wt[16];

  float4 gv[4];
#pragma unroll
  for (int i = 0; i < 4; ++i)
    gv[i] = *(const float4*)(gatesT + (size_t)e * N_TOK + t * 16 + i * 4);
  const float* g = (const float*)gv;
  int m[16];
  int s = 0;
#pragma unroll
  for (int i = 0; i < 16; ++i) {
    m[i] = (g[i] >= 0.f) ? 1 : 0;
    s += m[i];
  }

  int v = s;  // inclusive wave scan over thread sums
#pragma unroll
  for (int off = 1; off < 64; off <<= 1) {
    int u = __shfl_up(v, off, 64);
    if (lane >= off) v += u;
  }
  if (lane == 63) wt[w] = v;
  __syncthreads();
  int woff = 0;
#pragma unroll
  for (int i = 0; i < 16; ++i)
    if (i < w) woff += wt[i];

  int pos = woff + v - s;  // exclusive prefix for this thread's 16 tokens
#pragma unroll
  for (int i = 0; i < 16; ++i) {
    if (m[i] && pos < CAPACITY) {
      tok[e * CAPACITY + pos] = t * 16 + i;
      gslot[e * CAPACITY + pos] = g[i];
    }
    pos += m[i];
  }
}

// ---------------- load-balance loss: one block per expert ----------------
__global__ void frac_kernel(const float* __restrict__ gatesT,
                            float* __restrict__ fracsum) {
  __shared__ float red[256];
  const int e = blockIdx.x, t = threadIdx.x;
  float s = 0.f;
#pragma unroll
  for (int i = 0; i < 16; ++i) {
    float4 v = *(const float4*)(gatesT + (size_t)e * N_TOK + (i * 256 + t) * 4);
    s += fmaxf(v.x, 0.f) + fmaxf(v.y, 0.f) + fmaxf(v.z, 0.f) + fmaxf(v.w, 0.f);
  }
  red[t] = s;
  __syncthreads();
  for (int off = 128; off; off >>= 1) {
    if (t < off) red[t] += red[t + off];
    __syncthreads();
  }
  if (t == 0) fracsum[e] = red[0];
}

__global__ void lb_kernel(const float* __restrict__ fracsum,
                          float* __restrict__ out_scalar) {
  if (threadIdx.x == 0) {
    float s = 0.f;
#pragma unroll
    for (int e = 0; e < E_NUM; ++e) {
      float f = fracsum[e] / (float)N_TOK - 0.125f;
      s += f * f;
    }
    out_scalar[0] = LB_W * (s / (float)E_NUM);
  }
}

// ---------------- fp32 (E,R,S) -> bf16 (E,S,R) transpose+convert -------------
__global__ void transpose_cvt(const float* __restrict__ src,
                              bf16* __restrict__ dst, int R, int S) {
  __shared__ float tile[32][33];
  const int e = blockIdx.z;
  const int r0 = blockIdx.y * 32;
  const int s0 = blockIdx.x * 32;
  const int t = threadIdx.x;  // 256
  const int rr = t >> 3, cc = (t & 7) * 4;
  const float4 v = *(const float4*)(src + ((size_t)e * R + (r0 + rr)) * S + s0 + cc);
  tile[rr][cc + 0] = v.x;
  tile[rr][cc + 1] = v.y;
  tile[rr][cc + 2] = v.z;
  tile[rr][cc + 3] = v.w;
  __syncthreads();
  bf16x4 o;
#pragma unroll
  for (int i = 0; i < 4; ++i) o[i] = (bf16)tile[cc + i][rr];
  *(bf16x4*)(dst + ((size_t)e * S + (s0 + rr)) * R + r0 + cc) = o;
}

// ---------------- gather selected token rows into xe (bf16) -----------------
__global__ void gather_xe(const float* __restrict__ x,
                          const int* __restrict__ tok, bf16* __restrict__ xe) {
  const int row = blockIdx.x;  // e*CAP + slot
  const int t = tok[row];
  const int c = threadIdx.x * 8;  // 128 threads * 8 = 1024
  bf16x8 v;
  if (t >= 0) {
    const float4* xp = (const float4*)(x + (size_t)t * C_DIM + c);
    float4 a = xp[0], b = xp[1];
    v[0] = (bf16)a.x; v[1] = (bf16)a.y; v[2] = (bf16)a.z; v[3] = (bf16)a.w;
    v[4] = (bf16)b.x; v[5] = (bf16)b.y; v[6] = (bf16)b.z; v[7] = (bf16)b.w;
  } else {
#pragma unroll
    for (int i = 0; i < 8; ++i) v[i] = (bf16)0.f;
  }
  *(bf16x8*)(xe + (size_t)row * C_DIM + c) = v;
}

// ------ m97-style bf16 GEMM, expert-batched over blockIdx.z, XCD-swizzled ---
// C = A(MxK,kfast) * B(NxK,kfast)^T per z-slice
// EPI=0: Hout = bf16(relu(acc + bias[col]))
// EPI=1: if tok[row]>=0: atomicAdd(Out[tok[row]*C + col], gslot[row]*(acc+bias[col]))
template <int EPI>
__global__ __launch_bounds__(256) void gemm_bt(
    const bf16* __restrict__ A0, size_t aStride, const bf16* __restrict__ B0,
    size_t bStride, int Kk, int Nn, const float* __restrict__ bias0,
    int biasStride, bf16* __restrict__ Hout0, size_t hStride,
    const int* __restrict__ tok0, const float* __restrict__ gslot0,
    float* __restrict__ Out) {
  const int z = blockIdx.z;
  const bf16* A = A0 + (size_t)z * aStride;
  const bf16* B = B0 + (size_t)z * bStride;
  const float* bias = bias0 + (size_t)z * biasStride;

  // XCD-locality swizzle: XCD k (= linear id % 8 round-robin) takes a
  // contiguous y-stripe and sweeps x within it -> A-panels stay in its L2.
  const int nbid = blockIdx.y * gridDim.x + blockIdx.x;
  const int per = (gridDim.x * gridDim.y) >> 3;  // grid x*y divisible by 8
  const int lin = (nbid & 7) * per + (nbid >> 3);
  const int bm = (lin / gridDim.x) * 128;
  const int bn = (lin % gridDim.x) * 128;

  __shared__ bf16 As[128 * 32];
  __shared__ bf16 Bs[128 * 32];
  const int t = threadIdx.x;
  const int lane = t & 63;
  const int w = t >> 6;
  const int wm = (w >> 1) * 64;
  const int wn = (w & 1) * 64;

  f32x4 acc[4][4] = {};

  const int rowA = t >> 2;         // 0..63
  const int partA = (t & 3) << 4;  // byte offset within 64B row
  const char* aP1 = (const char*)(A + (size_t)(bm + rowA) * Kk) + partA;
  const char* aP2 = (const char*)(A + (size_t)(bm + 64 + rowA) * Kk) + partA;
  const char* bP1 = (const char*)(B + (size_t)(bn + rowA) * Kk) + partA;
  const char* bP2 = (const char*)(B + (size_t)(bn + 64 + rowA) * Kk) + partA;
  char* asD1 = (char*)As + (t & 192) * 16;
  char* asD2 = (char*)As + 4096 + (t & 192) * 16;
  char* bsD1 = (char*)Bs + (t & 192) * 16;
  char* bsD2 = (char*)Bs + 4096 + (t & 192) * 16;

  for (int kt = 0; kt < Kk; kt += 32) {
    gld_lds16(aP1 + kt * 2, asD1);
    gld_lds16(aP2 + kt * 2, asD2);
    gld_lds16(bP1 + kt * 2, bsD1);
    gld_lds16(bP2 + kt * 2, bsD2);
    __syncthreads();
    bf16x8 af[4], bfr[4];
#pragma unroll
    for (int i = 0; i < 4; ++i) {
      af[i] = *(const bf16x8*)(As + (wm + i * 16 + (lane & 15)) * 32 + (lane >> 4) * 8);
      bfr[i] = *(const bf16x8*)(Bs + (wn + i * 16 + (lane & 15)) * 32 + (lane >> 4) * 8);
    }
#pragma unroll
    for (int i = 0; i < 4; ++i)
#pragma unroll
      for (int j = 0; j < 4; ++j)
        acc[i][j] = __builtin_amdgcn_mfma_f32_16x16x32_bf16(af[i], bfr[j], acc[i][j], 0, 0, 0);
    __syncthreads();
  }

  if (EPI == 0) {
    bf16* Hout = Hout0 + (size_t)z * hStride;
#pragma unroll
    for (int i = 0; i < 4; ++i) {
      const int rbase = bm + wm + i * 16 + (lane >> 4) * 4;
#pragma unroll
      for (int j = 0; j < 4; ++j) {
        const int col = bn + wn + j * 16 + (lane & 15);
        const float b = bias[col];
#pragma unroll
        for (int r = 0; r < 4; ++r) {
          float v = acc[i][j][r] + b;
          Hout[(size_t)(rbase + r) * Nn + col] = (bf16)fmaxf(v, 0.f);
        }
      }
    }
  } else {
    const int* tok = tok0 + (size_t)z * CAPACITY;
    const float* gslot = gslot0 + (size_t)z * CAPACITY;
#pragma unroll
    for (int i = 0; i < 4; ++i) {
      const int rbase = bm + wm + i * 16 + (lane >> 4) * 4;
#pragma unroll
      for (int r = 0; r < 4; ++r) {
        const int row = rbase + r;
        const int tk = tok[row];
        if (tk >= 0) {
          const float g = gslot[row];
#pragma unroll
          for (int j = 0; j < 4; ++j) {
            const int col = bn + wn + j * 16 + (lane & 15);
            atomicAdd(Out + (size_t)tk * C_DIM + col, g * (acc[i][j][r] + bias[col]));
          }
        }
      }
    }
  }
}

extern "C" void kernel_launch(void* const* d_in, const int* in_sizes, int n_in,
                              void* d_out, int out_size, void* d_ws,
                              size_t ws_size, hipStream_t stream) {
  const float* x = (const float*)d_in[0];
  const float* noise = (const float*)d_in[1];
  const float* w_route = (const float*)d_in[2];
  const float* b_route = (const float*)d_in[3];
  const float* w_noise = (const float*)d_in[4];
  const float* b_noise = (const float*)d_in[5];
  const float* w1 = (const float*)d_in[6];
  const float* b1 = (const float*)d_in[7];
  const float* w2 = (const float*)d_in[8];
  const float* b2 = (const float*)d_in[9];
  float* out = (float*)d_out;

  char* ws = (char*)d_ws;
  size_t off = 0;
  auto alloc = [&](size_t bytes) {
    char* p = ws + off;
    off += (bytes + 255) & ~(size_t)255;
    return p;
  };
  float* gatesT = (float*)alloc((size_t)N_TOK * E_NUM * 4);
  int* tok = (int*)alloc((size_t)E_NUM * CAPACITY * 4);
  float* gslot = (float*)alloc((size_t)E_NUM * CAPACITY * 4);
  float* fracsum = (float*)alloc(256);
  bf16* xe = (bf16*)alloc((size_t)E_NUM * CAPACITY * C_DIM * 2);
  bf16* w1t = (bf16*)alloc((size_t)E_NUM * H_DIM * C_DIM * 2);
  bf16* w2t = (bf16*)alloc((size_t)E_NUM * C_DIM * H_DIM * 2);

  // Adaptive expert-group size for the h buffer (32 MB/expert); graph-safe
  // because ws_size is constant across calls.
  const size_t hPer = (size_t)CAPACITY * H_DIM * 2;
  size_t hAvail = (ws_size > off) ? (ws_size - off) : 0;
  int G = (int)(hAvail / hPer);
  if (G > E_NUM) G = E_NUM;
  if (G < 1) return;      // insufficient scratch -> visible failure
  while (E_NUM % G) --G;  // uniform batches: G in {8,4,2,1}
  bf16* hbuf = (bf16*)alloc((size_t)G * hPer);

  hipMemsetAsync(d_out, 0, (size_t)out_size * 4, stream);
  hipMemsetAsync(tok, 0xFF, (size_t)E_NUM * CAPACITY * 4, stream);

  // weight transposes (no deps on routing)
  transpose_cvt<<<dim3(H_DIM / 32, C_DIM / 32, E_NUM), 256, 0, stream>>>(w1, w1t, C_DIM, H_DIM);
  transpose_cvt<<<dim3(C_DIM / 32, H_DIM / 32, E_NUM), 256, 0, stream>>>(w2, w2t, H_DIM, C_DIM);

  route_kernel<<<dim3(N_TOK / 4), dim3(64, 4), 0, stream>>>(
      x, noise, w_route, b_route, w_noise, b_noise, gatesT);
  scan_kernel<<<E_NUM, 1024, 0, stream>>>(gatesT, tok, gslot);
  frac_kernel<<<E_NUM, 256, 0, stream>>>(gatesT, fracsum);
  lb_kernel<<<1, 64, 0, stream>>>(fracsum, out + (size_t)N_TOK * C_DIM);

  gather_xe<<<E_NUM * CAPACITY, 128, 0, stream>>>(x, tok, xe);

  for (int e0 = 0; e0 < E_NUM; e0 += G) {
    gemm_bt<0><<<dim3(H_DIM / 128, CAPACITY / 128, G), 256, 0, stream>>>(
        xe + (size_t)e0 * CAPACITY * C_DIM, (size_t)CAPACITY * C_DIM,
        w1t + (size_t)e0 * H_DIM * C_DIM, (size_t)H_DIM * C_DIM,
        C_DIM, H_DIM, b1 + (size_t)e0 * H_DIM, H_DIM,
        hbuf, (size_t)CAPACITY * H_DIM, nullptr, nullptr, nullptr);
    gemm_bt<1><<<dim3(C_DIM / 128, CAPACITY / 128, G), 256, 0, stream>>>(
        hbuf, (size_t)CAPACITY * H_DIM,
        w2t + (size_t)e0 * C_DIM * H_DIM, (size_t)C_DIM * H_DIM,
        H_DIM, C_DIM, b2 + (size_t)e0 * C_DIM, C_DIM,
        nullptr, 0, tok + (size_t)e0 * CAPACITY, gslot + (size_t)e0 * CAPACITY, out);
  }
}